// Round 2
// baseline (362.965 us; speedup 1.0000x reference)
//
#include <hip/hip_runtime.h>
#include <math.h>

// ---------------------------------------------------------------------------
// QuantumPoolingLayer — single fused kernel.
// inputs:  (128, 32, 32, 512) f32   [b][i][j][m], m contiguous
// weights: (512, 2, 4, 3) f32       [m][layer][k][{phi,theta,omega}]
// out:     (128, 512) f32           z = <Z_0>
//
// Block = 256 threads = 32 float4-channel lanes (mc) x 8 row-workers (w).
// Grid  = 128 b x 4 channel-tiles (128 ch each) = 512 blocks (2 blocks/CU).
// Phase 1: each thread sums 4 rows x 32 cols into 4 quadrant partials
//          (2x2 qi/qj), coalesced float4 loads, 128 independent loads/thread.
// Phase 2: LDS-reduce over the 8 workers; 128 lanes run the 4-qubit circuit.
// No d_ws usage (LDS only), one launch.
// ---------------------------------------------------------------------------

#define B_DIM   128
#define M_DIM   512
#define PI_F    3.14159265358979323846f

struct Cpx { float x, y; };

template<int M>
__device__ __forceinline__ void apply1q(float* re, float* im,
                                        Cpx g00, Cpx g01, Cpx g10, Cpx g11) {
    #pragma unroll
    for (int s = 0; s < 16; ++s) {
        if (s & M) continue;
        int s1 = s | M;
        float ar = re[s],  ai = im[s];
        float br = re[s1], bi = im[s1];
        re[s]  = g00.x * ar - g00.y * ai + g01.x * br - g01.y * bi;
        im[s]  = g00.x * ai + g00.y * ar + g01.x * bi + g01.y * br;
        re[s1] = g10.x * ar - g10.y * ai + g11.x * br - g11.y * bi;
        im[s1] = g10.x * ai + g10.y * ar + g11.x * bi + g11.y * br;
    }
}

template<int MC, int MT>
__device__ __forceinline__ void cnot(float* re, float* im) {
    #pragma unroll
    for (int s = 0; s < 16; ++s) {
        if ((s & MC) && !(s & MT)) {
            int s1 = s | MT;
            float t;
            t = re[s]; re[s] = re[s1]; re[s1] = t;
            t = im[s]; im[s] = im[s1]; im[s1] = t;
        }
    }
}

__device__ __forceinline__ void rot_gate(float phi, float theta, float omega,
                                         Cpx& g00, Cpx& g01, Cpx& g10, Cpx& g11) {
    float st, ct, sa, ca, sd, cd;
    __sincosf(0.5f * theta, &st, &ct);
    __sincosf(0.5f * (phi + omega), &sa, &ca);
    __sincosf(0.5f * (phi - omega), &sd, &cd);
    g00.x =  ca * ct;  g00.y = -sa * ct;
    g01.x = -cd * st;  g01.y = -sd * st;
    g10.x =  cd * st;  g10.y = -sd * st;
    g11.x =  ca * ct;  g11.y =  sa * ct;
}

__global__ __launch_bounds__(256)
void qpool_fused_kernel(const float* __restrict__ in, const float* __restrict__ qw,
                        float* __restrict__ out) {
    int blk = blockIdx.x;        // b*4 + mt
    int mt  = blk & 3;
    int b   = blk >> 2;
    int t   = threadIdx.x;
    int mc  = t & 31;            // float4 channel group within 128-ch tile
    int w   = t >> 5;            // row worker 0..7

    // ---------------- Phase 1: pooling ----------------
    const float4* in4 = (const float4*)in
        + (size_t)b * (32 * 32 * (M_DIM / 4)) + mt * 32 + mc;

    float4 acc[2][2];
    #pragma unroll
    for (int qi = 0; qi < 2; ++qi)
        #pragma unroll
        for (int qj = 0; qj < 2; ++qj)
            acc[qi][qj] = make_float4(0.f, 0.f, 0.f, 0.f);

    #pragma unroll
    for (int qi = 0; qi < 2; ++qi) {
        #pragma unroll
        for (int rh = 0; rh < 2; ++rh) {
            int i = qi * 16 + rh * 8 + w;
            const float4* row = in4 + (size_t)i * (32 * (M_DIM / 4));
            #pragma unroll
            for (int j = 0; j < 32; ++j) {
                float4 v = row[j * (M_DIM / 4)];
                int qj = j >> 4;   // compile-time under unroll
                acc[qi][qj].x += v.x; acc[qi][qj].y += v.y;
                acc[qi][qj].z += v.z; acc[qi][qj].w += v.w;
            }
        }
    }

    // ---------------- LDS reduction over 8 workers ----------------
    __shared__ float4 lds[8][2][2][32];   // 16 KiB
    #pragma unroll
    for (int qi = 0; qi < 2; ++qi)
        #pragma unroll
        for (int qj = 0; qj < 2; ++qj)
            lds[w][qi][qj][mc] = acc[qi][qj];
    __syncthreads();

    // ---------------- Phase 2: circuit (128 lanes) ----------------
    if (t < 128) {
        int c = t;                       // channel within tile
        int m = mt * 128 + c;            // global channel

        float ang[4];
        const float* ldsf = (const float*)lds;
        #pragma unroll
        for (int qi = 0; qi < 2; ++qi) {
            #pragma unroll
            for (int qj = 0; qj < 2; ++qj) {
                float s = 0.f;
                #pragma unroll
                for (int ww = 0; ww < 8; ++ww) {
                    // float index: (((ww*2+qi)*2+qj)*32 + (c>>2))*4 + (c&3) == ...*128 + c
                    s += ldsf[(((ww * 2 + qi) * 2 + qj) * 128) + c];
                }
                ang[qi * 2 + qj] = tanhf(s * (1.0f / 256.0f)) * PI_F;
            }
        }

        // |0000> through RY(ang[k]) on wire k: real product state
        float cs[4], sn[4];
        #pragma unroll
        for (int k = 0; k < 4; ++k) __sincosf(0.5f * ang[k], &sn[k], &cs[k]);

        float re[16], im[16];
        #pragma unroll
        for (int s = 0; s < 16; ++s) {
            re[s] = ((s & 8) ? sn[0] : cs[0]) * ((s & 4) ? sn[1] : cs[1]) *
                    ((s & 2) ? sn[2] : cs[2]) * ((s & 1) ? sn[3] : cs[3]);
            im[s] = 0.f;
        }

        const float* wbase = qw + (size_t)m * 24;   // [m][layer][k][3]
        #pragma unroll
        for (int layer = 0; layer < 2; ++layer) {
            const float* wl = wbase + layer * 12;
            Cpx g00, g01, g10, g11;
            rot_gate(wl[0],  wl[1],  wl[2],  g00, g01, g10, g11); apply1q<8>(re, im, g00, g01, g10, g11);
            rot_gate(wl[3],  wl[4],  wl[5],  g00, g01, g10, g11); apply1q<4>(re, im, g00, g01, g10, g11);
            rot_gate(wl[6],  wl[7],  wl[8],  g00, g01, g10, g11); apply1q<2>(re, im, g00, g01, g10, g11);
            rot_gate(wl[9],  wl[10], wl[11], g00, g01, g10, g11); apply1q<1>(re, im, g00, g01, g10, g11);
            cnot<8, 4>(re, im);
            cnot<8, 2>(re, im);
            cnot<8, 1>(re, im);
            cnot<4, 2>(re, im);
            cnot<4, 1>(re, im);
            cnot<2, 1>(re, im);
        }

        float z = 0.f;
        #pragma unroll
        for (int s = 0; s < 16; ++s) {
            float p = re[s] * re[s] + im[s] * im[s];
            z += (s & 8) ? -p : p;
        }
        out[(size_t)b * M_DIM + m] = z;
    }
}

// ================================ launch ===================================
extern "C" void kernel_launch(void* const* d_in, const int* in_sizes, int n_in,
                              void* d_out, int out_size, void* d_ws, size_t ws_size,
                              hipStream_t stream) {
    const float* in = (const float*)d_in[0];   // (128,32,32,512) f32
    const float* qw = (const float*)d_in[1];   // (512,2,4,3) f32
    float* out = (float*)d_out;                // (128,512) f32

    (void)in_sizes; (void)n_in; (void)out_size; (void)d_ws; (void)ws_size;

    qpool_fused_kernel<<<B_DIM * 4, 256, 0, stream>>>(in, qw, out);
}